// Round 13
// baseline (241.303 us; speedup 1.0000x reference)
//
#include <hip/hip_runtime.h>
#include <hip/hip_bf16.h>

#define DIM 768
#define HEADS 12
#define HD 64
#define SEQ 2048
#define BATCH 4
#define BHN 48          // BATCH*HEADS
#define TOK 8192        // BATCH*SEQ

#if __has_builtin(__builtin_amdgcn_exp2f)
#define EXP2F __builtin_amdgcn_exp2f
#else
#define EXP2F exp2f
#endif
// exp(s*0.125) = 2^(s * 0.125 * log2(e)); folded into Q at the QKV epilogue.
#define EXP_C 0.1803368801111244f

using short8  = __attribute__((ext_vector_type(8))) short;
using short4v = __attribute__((ext_vector_type(4))) short;
using float4v = __attribute__((ext_vector_type(4))) float;

__device__ __forceinline__ short f2b(float f) {
    union { float f; unsigned u; } v; v.f = f;
    unsigned r = v.u + 0x7FFF + ((v.u >> 16) & 1);
    return (short)(r >> 16);
}
__device__ __forceinline__ float b2f(short s) {
    union { unsigned u; float f; } v;
    v.u = ((unsigned)(unsigned short)s) << 16;
    return v.f;
}
// pack two floats to bf16x2 (round-half-up) in ONE v_perm_b32 after the adds.
__device__ __forceinline__ unsigned pk2(float a, float b) {
    union { float f; unsigned u; } x, y; x.f = a; y.f = b;
    return __builtin_amdgcn_perm(x.u + 0x8000u, y.u + 0x8000u, 0x03020706u);
}

// async global->LDS copy, 16B per lane; LDS dest = uniform base + lane*16
typedef const __attribute__((address_space(1))) unsigned GU;
typedef __attribute__((address_space(3))) unsigned LU;
__device__ __forceinline__ void gload_lds16(const short* g, short* l) {
    __builtin_amdgcn_global_load_lds((GU*)g, (LU*)l, 16, 0, 0);
}

// ---------------- fp32 -> bf16 cast (+ Vsum zeroing), one launch ----------------
__global__ void cast_all(const float* __restrict__ x, const float* __restrict__ wq,
                         const float* __restrict__ wp,
                         short* __restrict__ xb, short* __restrict__ wqb,
                         short* __restrict__ wpb, float* __restrict__ Vsum,
                         int nx4, int nq4) {
    int i = blockIdx.x * 256 + threadIdx.x;
    if (i < BHN * 64) Vsum[i] = 0.f;
    const float* in; short* out; int j = i;
    if (i < nx4)            { in = x;  out = xb;  }
    else if (i < nx4 + nq4) { in = wq; out = wqb; j = i - nx4; }
    else                    { in = wp; out = wpb; j = i - nx4 - nq4; }
    float4 f = ((const float4*)in)[j];
    short4 o;
    o.x = f2b(f.x); o.y = f2b(f.y); o.z = f2b(f.z); o.w = f2b(f.w);
    ((short4*)out)[j] = o;
}

// ---------------- QKV GEMM, 128x128 tile, BK=64 (two 32-col subtiles) ----------------
// LDS-staged coalesced epilogue. Output layouts:
//  Q/K: [bh][ n*64 + ((d>>3)^(n&7))*8 + (d&7) ]  (attn's K LDS image, XOR for banks)
//  V (round-22): PLAIN permuted order, NO XOR — V is now read global->reg in attn,
//  so banks are irrelevant; each attn fragment is a dense 64B segment:
//    [bh][ t2*4096 + d*64 + c2*32 + slot32 ],  t2=n>>6, c2=(n>>5)&1, w=n&31,
//    slot32 = ((w&15)>>2)*8 + ((w>>4)&1)*4 + (w&3)
__global__ __launch_bounds__(256, 4)
void gemm_qkv(const short* __restrict__ A, const short* __restrict__ Bw,
              short* __restrict__ Qw, short* __restrict__ Kw, short* __restrict__ Vw,
              float* __restrict__ Vsum)
{
    __shared__ __align__(16) short SMEM[18432];   // 36.9 KB
    short* As = SMEM;            // [2][128*32]
    short* Bs = SMEM + 8192;     // [2][128*32]

    const int tid  = threadIdx.x;
    const int lane = tid & 63;
    const int wave = tid >> 6;
    const int wm = (wave >> 1) * 64, wn = (wave & 1) * 64;
    const int l15 = lane & 15, quad = lane >> 4;

    const int gid = blockIdx.x;
    const int w   = gid >> 3;
    const int ybl = (gid & 7) * 8 + (w & 7);   // 0..63 token block
    const int xbl = w >> 3;                    // 0..17 col block

    const bool vpart = (xbl >= 12);
    const short* rowsP = vpart ? (Bw + 1536 * 768) : A;   // Wv rows | x tokens
    const short* colsP = vpart ? A : Bw;                  // x tokens | W rows
    const int m0 = vpart ? (xbl - 12) * 128 : ybl * 128;
    const int n0 = vpart ? ybl * 128 : xbl * 128;
    const int K = DIM;

    float4v acc[4][4];
    #pragma unroll
    for (int i = 0; i < 4; i++)
        #pragma unroll
        for (int j = 0; j < 4; j++)
            acc[i][j] = (float4v){0.f, 0.f, 0.f, 0.f};

    const int G0 = wave * 128 + lane;
    const int G1 = G0 + 64;
    const int rA0 = G0 >> 2, cA0 = (G0 & 3) * 8;
    const int rA1 = G1 >> 2, cA1 = (G1 & 3) * 8;
    const int ldsoff = wave * 1024;

    for (int kt = 0; kt < K; kt += 64) {
        #pragma unroll
        for (int s = 0; s < 2; s++) {
            const int kc = kt + s * 32;
            gload_lds16(&rowsP[(size_t)(m0 + rA0) * K + kc + cA0], &As[s * 4096 + ldsoff]);
            gload_lds16(&rowsP[(size_t)(m0 + rA1) * K + kc + cA1], &As[s * 4096 + ldsoff + 512]);
            gload_lds16(&colsP[(size_t)(n0 + rA0) * K + kc + cA0], &Bs[s * 4096 + ldsoff]);
            gload_lds16(&colsP[(size_t)(n0 + rA1) * K + kc + cA1], &Bs[s * 4096 + ldsoff + 512]);
        }
        __syncthreads();
        #pragma unroll
        for (int s = 0; s < 2; s++) {
            short8 af[4], bfr[4];
            #pragma unroll
            for (int t = 0; t < 4; t++) {
                af[t]  = *(const short8*)&As[s * 4096 + (wm + t * 16 + l15) * 32 + quad * 8];
                bfr[t] = *(const short8*)&Bs[s * 4096 + (wn + t * 16 + l15) * 32 + quad * 8];
            }
            #pragma unroll
            for (int tm = 0; tm < 4; tm++)
                #pragma unroll
                for (int tn = 0; tn < 4; tn++)
                    acc[tm][tn] = __builtin_amdgcn_mfma_f32_16x16x32_bf16(af[tm], bfr[tn], acc[tm][tn], 0, 0, 0);
        }
        __syncthreads();
    }

    if (!vpart) {
        // ---- Q/K epilogue: stage rows (stride 136) in final swizzled d-order ----
        const int g = wave & 1;   // which 64-col head group this wave owns
        #pragma unroll
        for (int tm = 0; tm < 4; tm++)
            #pragma unroll
            for (int tn = 0; tn < 4; tn++)
                #pragma unroll
                for (int r = 0; r < 4; r++) {
                    int lr = wm + tm * 16 + quad * 4 + r;
                    int d  = tn * 16 + l15;
                    float v = acc[tm][tn][r];
                    short o = (xbl < 6) ? f2b(v * EXP_C) : f2b(v);
                    SMEM[lr * 136 + g * 64 + (((d >> 3) ^ (lr & 7)) << 3) + (d & 7)] = o;
                }
        __syncthreads();
        short* base = (xbl < 6) ? Qw : Kw;
        const int hh0 = ((xbl < 6) ? xbl : xbl - 6) * 2;
        const int b = m0 >> 11;
        #pragma unroll
        for (int g2 = 0; g2 < 2; g2++) {
            short* dst = base + ((size_t)(b * HEADS + hh0 + g2)) * (SEQ * 64);
            #pragma unroll
            for (int it = 0; it < 4; it++) {
                int lr = it * 32 + (tid >> 3);
                short8 vv = *(const short8*)&SMEM[lr * 136 + g2 * 64 + (tid & 7) * 8];
                *(short8*)&dst[(size_t)(m0 + lr) * 64 + (tid & 7) * 8] = vv;
            }
        }
    } else {
        // ---- V epilogue: 4 regions (head-half g x token-half th), stride 72 ----
        // round-22: NO XOR — plain permuted slot order within each 64-short d-row.
        const int g  = wave >> 1;   // head half (from wm)
        const int th = wave & 1;    // token half (from wn)
        #pragma unroll
        for (int tm = 0; tm < 4; tm++)
            #pragma unroll
            for (int tn = 0; tn < 4; tn++)
                #pragma unroll
                for (int r = 0; r < 4; r++) {
                    int d = tm * 16 + quad * 4 + r;             // 0..63 within head
                    int g2v = (tn >> 1) * 4 + (l15 >> 2);       // c2*4 + (slot32>>3)
                    int off = (g2v << 3) + ((tn & 1) << 2) + (l15 & 3);
                    SMEM[(g * 2 + th) * 4608 + d * 72 + off] = f2b(acc[tm][tn][r]);
                }
        __syncthreads();
        const int b2 = n0 >> 11;
        #pragma unroll
        for (int reg = 0; reg < 4; reg++) {
            int gg = reg >> 1, t2h = reg & 1;
            int hh = (xbl - 12) * 2 + gg;
            short* dst = Vw + ((size_t)(b2 * HEADS + hh)) * (SEQ * 64)
                            + (size_t)((n0 >> 6) + t2h) * 4096;
            #pragma unroll
            for (int it = 0; it < 2; it++) {
                int d = it * 32 + (tid >> 3);
                short8 vv = *(const short8*)&SMEM[reg * 4608 + d * 72 + (tid & 7) * 8];
                *(short8*)&dst[d * 64 + (tid & 7) * 8] = vv;
            }
        }
        // fused vsum: partial column sums over this block's 64 tokens
        #pragma unroll
        for (int tm = 0; tm < 4; tm++)
            #pragma unroll
            for (int r = 0; r < 4; r++) {
                float s4 = (acc[tm][0][r] + acc[tm][1][r]) + (acc[tm][2][r] + acc[tm][3][r]);
                #pragma unroll
                for (int m = 1; m < 16; m <<= 1) s4 += __shfl_xor(s4, m, 64);
                if (l15 == 0) {
                    int row = m0 + wm + tm * 16 + quad * 4 + r;
                    int hh = row >> 6, d = row & 63;
                    atomicAdd(&Vsum[(b2 * HEADS + hh) * 64 + d], s4);
                }
            }
    }
}

// ---------------- proj GEMM, 128x64 tile, BK=32 ring-of-3 pipeline ----------------
__global__ __launch_bounds__(256, 4)
void gemm_proj(const short* __restrict__ A, const short* __restrict__ Bw,
               const float* __restrict__ bias, float* __restrict__ Out)
{
    __shared__ __align__(16) short As[3][128 * 32];   // 24 KB
    __shared__ __align__(16) short Bs[3][64 * 32];    // 12 KB -> 36 KB total

    const int tid  = threadIdx.x;
    const int lane = tid & 63;
    const int wave = tid >> 6;
    const int wm = (wave >> 1) * 64, wn = (wave & 1) * 32;
    const int l15 = lane & 15, quad = lane >> 4;

    const int gid = blockIdx.x;             // 0..767
    const int w   = gid >> 3;               // 0..95
    const int ybl = (gid & 7) * 8 + (w & 7);   // 0..63 token block
    const int xbl = w >> 3;                    // 0..11 col block
    const int m0 = ybl * 128, n0 = xbl * 64;
    const int K = DIM;

    float4v acc[4][2];
    #pragma unroll
    for (int i = 0; i < 4; i++)
        #pragma unroll
        for (int j = 0; j < 2; j++)
            acc[i][j] = (float4v){0.f, 0.f, 0.f, 0.f};

    const int GA0 = wave * 128 + lane, GA1 = GA0 + 64;
    const int rA0 = GA0 >> 2, cA0 = (GA0 & 3) * 8;
    const int rA1 = GA1 >> 2, cA1 = (GA1 & 3) * 8;
    const int GB0 = wave * 64 + lane;
    const int rB0 = GB0 >> 2, cB0 = (GB0 & 3) * 8;
    const int ldsoffA = wave * 1024, ldsoffB = wave * 512;

    // stage K-step t into ring buffer buf: 3 DMAs per wave (2 A + 1 B)
    auto STAGE = [&](int t, int buf) {
        const int kc = t * 32;
        gload_lds16(&A [(size_t)(m0 + rA0) * K + kc + cA0], &As[buf][ldsoffA]);
        gload_lds16(&A [(size_t)(m0 + rA1) * K + kc + cA1], &As[buf][ldsoffA + 512]);
        gload_lds16(&Bw[(size_t)(n0 + rB0) * K + kc + cB0], &Bs[buf][ldsoffB]);
    };

    STAGE(0, 0);
    STAGE(1, 1);

    int cur = 0, nx2 = 2;
    for (int t = 0; t < 24; t++) {
        if (t < 23) { asm volatile("s_waitcnt vmcnt(3)" ::: "memory"); }
        else        { asm volatile("s_waitcnt vmcnt(0)" ::: "memory"); }
        __builtin_amdgcn_sched_barrier(0);
        __builtin_amdgcn_s_barrier();
        __builtin_amdgcn_sched_barrier(0);

        short8 af[4], bfr[2];
        #pragma unroll
        for (int tt = 0; tt < 4; tt++)
            af[tt] = *(const short8*)&As[cur][(wm + tt * 16 + l15) * 32 + quad * 8];
        #pragma unroll
        for (int tt = 0; tt < 2; tt++)
            bfr[tt] = *(const short8*)&Bs[cur][(wn + tt * 16 + l15) * 32 + quad * 8];
        #pragma unroll
        for (int tm = 0; tm < 4; tm++)
            #pragma unroll
            for (int tn = 0; tn < 2; tn++)
                acc[tm][tn] = __builtin_amdgcn_mfma_f32_16x16x32_bf16(af[tm], bfr[tn], acc[tm][tn], 0, 0, 0);

        if (t < 22) STAGE(t + 2, nx2);
        cur = (cur == 2) ? 0 : cur + 1;
        nx2 = (nx2 == 2) ? 0 : nx2 + 1;
    }

    #pragma unroll
    for (int tm = 0; tm < 4; tm++)
        #pragma unroll
        for (int tn = 0; tn < 2; tn++)
            #pragma unroll
            for (int r = 0; r < 4; r++) {
                int row = m0 + wm + tm * 16 + quad * 4 + r;
                int col = n0 + wn + tn * 16 + l15;
                Out[(size_t)row * 768 + col] = acc[tm][tn][r] + bias[col];
            }
}

// ---------------- fused double-softmax attention ----------------
// Round-22: V reads go global->register (LDS only holds K).
//  - 256 threads, 4 waves x 32 q-rows (r9 base — best measured).
//  - K ring of 3 x 8KB = 24 KB LDS, 2 DMAs/wave/kt, one s_barrier per kt.
//  - Per kt: barrier -> issue 8 V global b128 loads (dense 64B segments,
//    L2-resident) -> QK+exp (hides V latency) -> STAGE(kt+2) -> vmcnt(2)
//    (FIFO: the 2 allowed-outstanding are the newest = K(kt+2); V(kt) and
//    K(kt+1) are older, hence complete) -> PV.
//  - This halves LDS-port traffic (16->8 b128 reads/wave/kt) — the binding
//    resource identified in round 12 — and halves staging DMAs.
__global__ __launch_bounds__(256, 3)
void attn_kernel(const short* __restrict__ Qw, const short* __restrict__ Kw,
                 const short* __restrict__ Vw, const float* __restrict__ Vsum,
                 short* __restrict__ Ow)
{
    __shared__ __align__(16) short LDS[12288];  // 24 KB: K[3][4096] (Q image fits in [0,8192))

    const int tid  = threadIdx.x;
    const int lane = tid & 63, wave = tid >> 6;
    const int l15 = lane & 15, quad = lane >> 4;
    const int r7  = l15 & 7;
    // XCD-locality: 6 heads per XCD; the 16 q-blocks of a head share its K/V in L2.
    const int bid = blockIdx.x;
    const int ii  = bid >> 3;                  // 0..95
    const int bh  = (bid & 7) * 6 + (ii >> 4); // head
    const int qt  = ii & 15;                   // q-tile index
    const int wq  = wave * 32;                 // wave's q-row base within block

    const short* Qp = Qw + (size_t)bh * (SEQ * 64) + qt * 8192;
    const short* Kp = Kw + (size_t)bh * (SEQ * 64);
    const short* Vp = Vw + (size_t)bh * (SEQ * 64);

    // ones B-fragment for 16x16x32: col 0 only (l15==0), all 8 k-slots = 1.0
    short8 onesf;
    #pragma unroll
    for (int j = 0; j < 8; j++) onesf[j] = (l15 == 0) ? (short)0x3F80 : (short)0;

    // ---- stage Q tile image (16 granules), read fragments, then free the LDS ----
    #pragma unroll
    for (int h = 0; h < 4; h++) {
        const int g = wave * 4 + h;
        gload_lds16(&Qp[g * 512 + lane * 8], &LDS[g * 512]);
    }
    __syncthreads();   // full drain ok here (prologue only)
    short8 aq[2][2];
    #pragma unroll
    for (int nb = 0; nb < 2; nb++)
        #pragma unroll
        for (int kk = 0; kk < 2; kk++) {
            int r = wq + nb * 16 + l15;
            aq[nb][kk] = *(const short8*)&LDS[r * 64 + (((kk * 4 + quad) ^ r7) << 3)];
        }
    __syncthreads();   // all waves done reading Q before K staging overwrites

    float4v Aacc[2][4], Lacc[2];
    #pragma unroll
    for (int mb = 0; mb < 2; mb++) {
        Lacc[mb] = (float4v){0.f, 0.f, 0.f, 0.f};
        #pragma unroll
        for (int t = 0; t < 4; t++) Aacc[mb][t] = (float4v){0.f, 0.f, 0.f, 0.f};
    }

    // stage(t2) -> K ring buffer kbuf: 2 K-granules per wave (2 DMAs)
    auto STAGE = [&](int t2, int kbuf) {
        const int kb = kbuf * 4096;
        #pragma unroll
        for (int h = 0; h < 2; h++) {
            const int g = wave * 2 + h;
            gload_lds16(&Kp[(size_t)t2 * 4096 + g * 512 + lane * 8], &LDS[kb + g * 512]);
        }
    };

    STAGE(0, 0);
    STAGE(1, 1);
    asm volatile("s_waitcnt vmcnt(2)" ::: "memory");   // K(0) resident (own granules)
    __builtin_amdgcn_sched_barrier(0);

    // per-lane V offset within a 64-key half-tile row-group (shorts)
    const int vlq = l15 * 64 + quad * 8;   // (d&15)*64 + quad*8; tn adds 16*64, c2 adds 32

    int cur = 0, nx2 = 2;   // kt%3 and (kt+2)%3
    for (int kt = 0; kt < 32; kt++) {
        __builtin_amdgcn_s_barrier();          // stage(kt) resident (prev vmcnt); kt-1 reads done
        __builtin_amdgcn_sched_barrier(0);

        const short* KB = &LDS[cur * 4096];

        // issue this tile's V loads early; latency hides under QK+exp
        short8 bv[2][4];
        #pragma unroll
        for (int c2 = 0; c2 < 2; c2++)
            #pragma unroll
            for (int tn = 0; tn < 4; tn++)
                bv[c2][tn] = *(const short8*)&Vp[(size_t)kt * 4096 + tn * 1024 + c2 * 32 + vlq];

        union AE { unsigned u[4]; short8 s; };
        AE ae[2][2];   // [c2][nb]
        #pragma unroll
        for (int c2 = 0; c2 < 2; c2++)
            #pragma unroll
            for (int tn2 = 0; tn2 < 2; tn2++) {
                const int row = (c2 * 2 + tn2) * 16 + l15;
                const short* rp = &KB[row * 64];
                short8 b0 = *(const short8*)&rp[(quad ^ r7) << 3];
                short8 b1 = *(const short8*)&rp[((4 + quad) ^ r7) << 3];
                #pragma unroll
                for (int nb = 0; nb < 2; nb++) {
                    float4v s = (float4v){0.f, 0.f, 0.f, 0.f};
                    s = __builtin_amdgcn_mfma_f32_16x16x32_bf16(b0, aq[nb][0], s, 0, 0, 0);
                    s = __builtin_amdgcn_mfma_f32_16x16x32_bf16(b1, aq[nb][1], s, 0, 0, 0);
                    ae[c2][nb].u[tn2 * 2]     = pk2(EXP2F(s[0]), EXP2F(s[1]));
                    ae[c2][nb].u[tn2 * 2 + 1] = pk2(EXP2F(s[2]), EXP2F(s[3]));
                }
            }

        if (kt < 30) STAGE(kt + 2, nx2);       // overwrite buffer last read at kt-1
        if (kt < 30) { asm volatile("s_waitcnt vmcnt(2)" ::: "memory"); }
        else         { asm volatile("s_waitcnt vmcnt(0)" ::: "memory"); }
        __builtin_amdgcn_sched_barrier(0);

        __builtin_amdgcn_s_setprio(1);
        #pragma unroll
        for (int c2 = 0; c2 < 2; c2++) {
            Lacc[0] = __builtin_amdgcn_mfma_f32_16x16x32_bf16(ae[c2][0].s, onesf, Lacc[0], 0, 0, 0);
            Lacc[1] = __builtin_amdgcn_mfma_f32_16x16x32_bf16(ae[c2][1].s, onesf, Lacc[1], 0, 0, 0);
            #pragma unroll
            for (int tn = 0; tn < 4; tn++) {
                Aacc[0][tn] = __builtin_amdgcn_mfma_f32_16x16x32_bf16(ae[c2][0].s, bv[c2][tn], Aacc[0][tn], 0, 0, 0);
                Aacc[1][tn] = __builtin_amdgcn_mfma_f32_16x16x32_bf16(ae[c2][1].s, bv[c2][tn], Aacc[1][tn], 0, 0, 0);
            }
        }
        __builtin_amdgcn_s_setprio(0);

        cur = (cur == 2) ? 0 : cur + 1;
        nx2 = (nx2 == 2) ? 0 : nx2 + 1;
    }

    // epilogue: wave-local. Lacc[mb][r] (at l15==0) is already the FULL row sum.
    const int b = bh / HEADS, hh = bh - (bh / HEADS) * HEADS;
    #pragma unroll
    for (int mb = 0; mb < 2; mb++)
        #pragma unroll
        for (int r = 0; r < 4; r++) {
            float il = 1.f / __shfl(Lacc[mb][r], lane & 48, 64);
            int row = qt * 128 + wq + mb * 16 + quad * 4 + r;
            int tok = b * SEQ + row;
            #pragma unroll
            for (int tn = 0; tn < 4; tn++) {
                int d = tn * 16 + l15;
                float vs = Vsum[bh * 64 + d];
                float val = (vs + Aacc[mb][tn][r] * il) * (1.f / 2049.f);
                Ow[(size_t)tok * 768 + hh * 64 + d] = f2b(val);
            }
        }
}

extern "C" void kernel_launch(void* const* d_in, const int* in_sizes, int n_in,
                              void* d_out, int out_size, void* d_ws, size_t ws_size,
                              hipStream_t stream) {
    const float* x      = (const float*)d_in[0];
    const float* w_qkv  = (const float*)d_in[1];
    const float* w_proj = (const float*)d_in[2];
    const float* b_proj = (const float*)d_in[3];
    float* out = (float*)d_out;

    char* ws = (char*)d_ws;
    size_t off = 0;
    auto alloc = [&](size_t bytes) {
        void* p = ws + off;
        off += (bytes + 255) & ~(size_t)255;
        return p;
    };
    short* x_bf  = (short*)alloc((size_t)TOK * DIM * 2);
    short* wq_bf = (short*)alloc((size_t)3 * DIM * DIM * 2);
    short* wp_bf = (short*)alloc((size_t)DIM * DIM * 2);
    short* Qw    = (short*)alloc((size_t)BHN * SEQ * 64 * 2);
    short* Kw    = (short*)alloc((size_t)BHN * SEQ * 64 * 2);
    short* Vw    = (short*)alloc((size_t)BHN * SEQ * 64 * 2);
    short* Ow    = (short*)alloc((size_t)TOK * DIM * 2);
    float* Vsum  = (float*)alloc((size_t)BHN * 64 * 4);

    int nx4 = TOK * DIM / 4, nq4 = 3 * DIM * DIM / 4, np4 = DIM * DIM / 4;
    int tot4 = nx4 + nq4 + np4;
    cast_all<<<tot4 / 256, 256, 0, stream>>>(x, w_qkv, w_proj, x_bf, wq_bf, wp_bf, Vsum, nx4, nq4);

    gemm_qkv<<<1152, 256, 0, stream>>>(x_bf, wq_bf, Qw, Kw, Vw, Vsum);

    attn_kernel<<<BHN * 16, 256, 0, stream>>>(Qw, Kw, Vw, Vsum, Ow);

    gemm_proj<<<768, 256, 0, stream>>>(Ow, wp_bf, b_proj, out);
}

// Round 14
// 198.671 us; speedup vs baseline: 1.2146x; 1.2146x over previous
//
#include <hip/hip_runtime.h>
#include <hip/hip_bf16.h>

#define DIM 768
#define HEADS 12
#define HD 64
#define SEQ 2048
#define BATCH 4
#define BHN 48          // BATCH*HEADS
#define TOK 8192        // BATCH*SEQ

#if __has_builtin(__builtin_amdgcn_exp2f)
#define EXP2F __builtin_amdgcn_exp2f
#else
#define EXP2F exp2f
#endif
// exp(s*0.125) = 2^(s * 0.125 * log2(e)); folded into Q at the QKV epilogue.
#define EXP_C 0.1803368801111244f

using short8  = __attribute__((ext_vector_type(8))) short;
using short4v = __attribute__((ext_vector_type(4))) short;
using float4v = __attribute__((ext_vector_type(4))) float;

__device__ __forceinline__ short f2b(float f) {
    union { float f; unsigned u; } v; v.f = f;
    unsigned r = v.u + 0x7FFF + ((v.u >> 16) & 1);
    return (short)(r >> 16);
}
__device__ __forceinline__ float b2f(short s) {
    union { unsigned u; float f; } v;
    v.u = ((unsigned)(unsigned short)s) << 16;
    return v.f;
}
// pack two floats to bf16x2 (round-half-up) in ONE v_perm_b32 after the adds.
__device__ __forceinline__ unsigned pk2(float a, float b) {
    union { float f; unsigned u; } x, y; x.f = a; y.f = b;
    return __builtin_amdgcn_perm(x.u + 0x8000u, y.u + 0x8000u, 0x03020706u);
}

// async global->LDS copy, 16B per lane; LDS dest = uniform base + lane*16
typedef const __attribute__((address_space(1))) unsigned GU;
typedef __attribute__((address_space(3))) unsigned LU;
__device__ __forceinline__ void gload_lds16(const short* g, short* l) {
    __builtin_amdgcn_global_load_lds((GU*)g, (LU*)l, 16, 0, 0);
}

// ---------------- fp32 -> bf16 cast (+ Vsum zeroing), one launch ----------------
__global__ void cast_all(const float* __restrict__ x, const float* __restrict__ wq,
                         const float* __restrict__ wp,
                         short* __restrict__ xb, short* __restrict__ wqb,
                         short* __restrict__ wpb, float* __restrict__ Vsum,
                         int nx4, int nq4) {
    int i = blockIdx.x * 256 + threadIdx.x;
    if (i < BHN * 64) Vsum[i] = 0.f;
    const float* in; short* out; int j = i;
    if (i < nx4)            { in = x;  out = xb;  }
    else if (i < nx4 + nq4) { in = wq; out = wqb; j = i - nx4; }
    else                    { in = wp; out = wpb; j = i - nx4 - nq4; }
    float4 f = ((const float4*)in)[j];
    short4 o;
    o.x = f2b(f.x); o.y = f2b(f.y); o.z = f2b(f.z); o.w = f2b(f.w);
    ((short4*)out)[j] = o;
}

// ---------------- QKV GEMM, 128x128 tile, BK=32 ring-of-3 pipeline ----------------
// T3+T4: 3 LDS buffers (48 KB), ONE s_barrier per K-step, counted vmcnt(4)
// (next step's 4 staging DMAs stay in flight across the barrier), STAGE(t+2)
// issued at step end overwrites the buffer last read at t-1.
// Output layouts: attn's pre-swizzled LDS images + fused Vsum.
__global__ __launch_bounds__(256, 3)
void gemm_qkv(const short* __restrict__ A, const short* __restrict__ Bw,
              short* __restrict__ Qw, short* __restrict__ Kw, short* __restrict__ Vw,
              float* __restrict__ Vsum)
{
    __shared__ __align__(16) short As[3][128 * 32];   // 24 KB
    __shared__ __align__(16) short Bs[3][128 * 32];   // 24 KB -> 48 KB total

    const int tid  = threadIdx.x;
    const int lane = tid & 63;
    const int wave = tid >> 6;
    const int wm = (wave >> 1) * 64, wn = (wave & 1) * 64;
    const int l15 = lane & 15, quad = lane >> 4;

    const int gid = blockIdx.x;
    const int w   = gid >> 3;
    const int ybl = (gid & 7) * 8 + (w & 7);   // 0..63 token block
    const int xbl = w >> 3;                    // 0..17 col block

    const bool vpart = (xbl >= 12);
    const short* rowsP = vpart ? (Bw + 1536 * 768) : A;   // Wv rows | x tokens
    const short* colsP = vpart ? A : Bw;                  // x tokens | W rows
    const int m0 = vpart ? (xbl - 12) * 128 : ybl * 128;
    const int n0 = vpart ? ybl * 128 : xbl * 128;
    const int K = DIM;

    float4v acc[4][4];
    #pragma unroll
    for (int i = 0; i < 4; i++)
        #pragma unroll
        for (int j = 0; j < 4; j++)
            acc[i][j] = (float4v){0.f, 0.f, 0.f, 0.f};

    const int G0 = wave * 128 + lane;
    const int G1 = G0 + 64;
    const int rA0 = G0 >> 2, cA0 = (G0 & 3) * 8;
    const int rA1 = G1 >> 2, cA1 = (G1 & 3) * 8;
    const int ldsoff = wave * 1024;

    // stage K-step t (32 cols) into ring buffer buf: 4 DMAs per wave
    auto STAGE = [&](int t, int buf) {
        const int kc = t * 32;
        gload_lds16(&rowsP[(size_t)(m0 + rA0) * K + kc + cA0], &As[buf][ldsoff]);
        gload_lds16(&rowsP[(size_t)(m0 + rA1) * K + kc + cA1], &As[buf][ldsoff + 512]);
        gload_lds16(&colsP[(size_t)(n0 + rA0) * K + kc + cA0], &Bs[buf][ldsoff]);
        gload_lds16(&colsP[(size_t)(n0 + rA1) * K + kc + cA1], &Bs[buf][ldsoff + 512]);
    };

    STAGE(0, 0);
    STAGE(1, 1);

    int cur = 0, nx2 = 2;
    for (int t = 0; t < 24; t++) {
        if (t < 23) { asm volatile("s_waitcnt vmcnt(4)" ::: "memory"); }
        else        { asm volatile("s_waitcnt vmcnt(0)" ::: "memory"); }
        __builtin_amdgcn_sched_barrier(0);
        __builtin_amdgcn_s_barrier();          // stage(t) resident; t-1 reads done
        __builtin_amdgcn_sched_barrier(0);

        short8 af[4], bfr[4];
        #pragma unroll
        for (int tt = 0; tt < 4; tt++) {
            af[tt]  = *(const short8*)&As[cur][(wm + tt * 16 + l15) * 32 + quad * 8];
            bfr[tt] = *(const short8*)&Bs[cur][(wn + tt * 16 + l15) * 32 + quad * 8];
        }
        #pragma unroll
        for (int tm = 0; tm < 4; tm++)
            #pragma unroll
            for (int tn = 0; tn < 4; tn++)
                acc[tm][tn] = __builtin_amdgcn_mfma_f32_16x16x32_bf16(af[tm], bfr[tn], acc[tm][tn], 0, 0, 0);

        if (t < 22) STAGE(t + 2, nx2);         // overwrite buffer last read at t-1
        cur = (cur == 2) ? 0 : cur + 1;
        nx2 = (nx2 == 2) ? 0 : nx2 + 1;
    }

    #pragma unroll
    for (int tm = 0; tm < 4; tm++)
        #pragma unroll
        for (int tn = 0; tn < 4; tn++)
            #pragma unroll
            for (int r = 0; r < 4; r++) {
                int row = m0 + wm + tm * 16 + quad * 4 + r;
                int col = n0 + wn + tn * 16 + l15;
                float v = acc[tm][tn][r];
                if (vpart) {
                    int hh = row >> 6, d = row & 63;
                    int b = col >> 11, n = col & 2047;
                    int bh = b * HEADS + hh;
                    int t2 = n >> 6, c2h = (n >> 5) & 1, wk = n & 31;
                    int slot = ((wk & 15) >> 2) * 8 + ((wk & 16) >> 2) + (wk & 3);
                    int g2 = c2h * 4 + (slot >> 3);
                    int gp2 = g2 ^ (d & 7);
                    Vw[(size_t)bh * (SEQ * 64) + t2 * 4096 + d * 64 + gp2 * 8 + (slot & 7)] = f2b(v);
                } else {
                    int hh = (col & 767) >> 6, d = col & 63;
                    int b = row >> 11, n = row & 2047;
                    int bh = b * HEADS + hh;
                    size_t idx = (size_t)bh * (SEQ * 64) + (size_t)n * 64
                               + (((d >> 3) ^ (n & 7)) << 3) + (d & 7);
                    if (col < 768) Qw[idx] = f2b(v * EXP_C);
                    else           Kw[idx] = f2b(v);
                }
            }

    // fused vsum: partial column sums over this block's 64 tokens (per wave-half)
    if (vpart) {
        const int bb = n0 >> 11;   // batch of this block's tokens
        #pragma unroll
        for (int tm = 0; tm < 4; tm++)
            #pragma unroll
            for (int r = 0; r < 4; r++) {
                float s4 = (acc[tm][0][r] + acc[tm][1][r]) + (acc[tm][2][r] + acc[tm][3][r]);
                #pragma unroll
                for (int m = 1; m < 16; m <<= 1) s4 += __shfl_xor(s4, m, 64);
                if (l15 == 0) {
                    int row = m0 + wm + tm * 16 + quad * 4 + r;
                    int hh = row >> 6, d = row & 63;
                    atomicAdd(&Vsum[(bb * HEADS + hh) * 64 + d], s4);
                }
            }
    }
}

// ---------------- proj GEMM, 128x64 tile, BK=32 ring-of-3 pipeline ----------------
__global__ __launch_bounds__(256, 4)
void gemm_proj(const short* __restrict__ A, const short* __restrict__ Bw,
               const float* __restrict__ bias, float* __restrict__ Out)
{
    __shared__ __align__(16) short As[3][128 * 32];   // 24 KB
    __shared__ __align__(16) short Bs[3][64 * 32];    // 12 KB -> 36 KB total

    const int tid  = threadIdx.x;
    const int lane = tid & 63;
    const int wave = tid >> 6;
    const int wm = (wave >> 1) * 64, wn = (wave & 1) * 32;
    const int l15 = lane & 15, quad = lane >> 4;

    const int gid = blockIdx.x;             // 0..767
    const int w   = gid >> 3;               // 0..95
    const int ybl = (gid & 7) * 8 + (w & 7);   // 0..63 token block
    const int xbl = w >> 3;                    // 0..11 col block
    const int m0 = ybl * 128, n0 = xbl * 64;
    const int K = DIM;

    float4v acc[4][2];
    #pragma unroll
    for (int i = 0; i < 4; i++)
        #pragma unroll
        for (int j = 0; j < 2; j++)
            acc[i][j] = (float4v){0.f, 0.f, 0.f, 0.f};

    const int GA0 = wave * 128 + lane, GA1 = GA0 + 64;
    const int rA0 = GA0 >> 2, cA0 = (GA0 & 3) * 8;
    const int rA1 = GA1 >> 2, cA1 = (GA1 & 3) * 8;
    const int GB0 = wave * 64 + lane;
    const int rB0 = GB0 >> 2, cB0 = (GB0 & 3) * 8;
    const int ldsoffA = wave * 1024, ldsoffB = wave * 512;

    // stage K-step t into ring buffer buf: 3 DMAs per wave (2 A + 1 B)
    auto STAGE = [&](int t, int buf) {
        const int kc = t * 32;
        gload_lds16(&A [(size_t)(m0 + rA0) * K + kc + cA0], &As[buf][ldsoffA]);
        gload_lds16(&A [(size_t)(m0 + rA1) * K + kc + cA1], &As[buf][ldsoffA + 512]);
        gload_lds16(&Bw[(size_t)(n0 + rB0) * K + kc + cB0], &Bs[buf][ldsoffB]);
    };

    STAGE(0, 0);
    STAGE(1, 1);

    int cur = 0, nx2 = 2;
    for (int t = 0; t < 24; t++) {
        if (t < 23) { asm volatile("s_waitcnt vmcnt(3)" ::: "memory"); }
        else        { asm volatile("s_waitcnt vmcnt(0)" ::: "memory"); }
        __builtin_amdgcn_sched_barrier(0);
        __builtin_amdgcn_s_barrier();
        __builtin_amdgcn_sched_barrier(0);

        short8 af[4], bfr[2];
        #pragma unroll
        for (int tt = 0; tt < 4; tt++)
            af[tt] = *(const short8*)&As[cur][(wm + tt * 16 + l15) * 32 + quad * 8];
        #pragma unroll
        for (int tt = 0; tt < 2; tt++)
            bfr[tt] = *(const short8*)&Bs[cur][(wn + tt * 16 + l15) * 32 + quad * 8];
        #pragma unroll
        for (int tm = 0; tm < 4; tm++)
            #pragma unroll
            for (int tn = 0; tn < 2; tn++)
                acc[tm][tn] = __builtin_amdgcn_mfma_f32_16x16x32_bf16(af[tm], bfr[tn], acc[tm][tn], 0, 0, 0);

        if (t < 22) STAGE(t + 2, nx2);
        cur = (cur == 2) ? 0 : cur + 1;
        nx2 = (nx2 == 2) ? 0 : nx2 + 1;
    }

    #pragma unroll
    for (int tm = 0; tm < 4; tm++)
        #pragma unroll
        for (int tn = 0; tn < 2; tn++)
            #pragma unroll
            for (int r = 0; r < 4; r++) {
                int row = m0 + wm + tm * 16 + quad * 4 + r;
                int col = n0 + wn + tn * 16 + l15;
                Out[(size_t)row * 768 + col] = acc[tm][tn][r] + bias[col];
            }
}

// ---------------- fused double-softmax attention ----------------
// Round-24 = round-9 restore (best measured, 59.5 us): 3-buffer 1-barrier
// ring, K+V both LDS-staged from pre-swizzled global images, MFMA L-sum.
// Round-13's V global->reg path regressed 2x (scattered 128B-stride lane
// pattern -> 16 L2 transactions per load + per-kt serial drain) — reverted.
__global__ __launch_bounds__(256, 3)
void attn_kernel(const short* __restrict__ Qw, const short* __restrict__ Kw,
                 const short* __restrict__ Vw, const float* __restrict__ Vsum,
                 short* __restrict__ Ow)
{
    __shared__ __align__(16) short LDS[24576];  // 48 KB: K[3][4096] | V[3][4096]

    const int tid  = threadIdx.x;
    const int lane = tid & 63, wave = tid >> 6;
    const int l15 = lane & 15, quad = lane >> 4;
    const int r7  = l15 & 7;
    // XCD-locality: 6 heads per XCD; the 16 q-blocks of a head share its K/V in L2.
    const int bid = blockIdx.x;
    const int ii  = bid >> 3;                  // 0..95
    const int bh  = (bid & 7) * 6 + (ii >> 4); // head
    const int qt  = ii & 15;                   // q-tile index
    const int wq  = wave * 32;                 // wave's q-row base within block

    const short* Qp = Qw + (size_t)bh * (SEQ * 64) + qt * 8192;
    const short* Kp = Kw + (size_t)bh * (SEQ * 64);
    const short* Vp = Vw + (size_t)bh * (SEQ * 64);

    // ones B-fragment for 16x16x32: col 0 only (l15==0), all 8 k-slots = 1.0
    short8 onesf;
    #pragma unroll
    for (int j = 0; j < 8; j++) onesf[j] = (l15 == 0) ? (short)0x3F80 : (short)0;

    // ---- stage Q tile image (16 granules), read fragments, then free the LDS ----
    #pragma unroll
    for (int h = 0; h < 4; h++) {
        const int g = wave * 4 + h;
        gload_lds16(&Qp[g * 512 + lane * 8], &LDS[g * 512]);
    }
    __syncthreads();   // full drain ok here (prologue only)
    short8 aq[2][2];
    #pragma unroll
    for (int nb = 0; nb < 2; nb++)
        #pragma unroll
        for (int kk = 0; kk < 2; kk++) {
            int r = wq + nb * 16 + l15;
            aq[nb][kk] = *(const short8*)&LDS[r * 64 + (((kk * 4 + quad) ^ r7) << 3)];
        }
    __syncthreads();   // all waves done reading Q before K/V staging overwrites

    float4v Aacc[2][4], Lacc[2];
    #pragma unroll
    for (int mb = 0; mb < 2; mb++) {
        Lacc[mb] = (float4v){0.f, 0.f, 0.f, 0.f};
        #pragma unroll
        for (int t = 0; t < 4; t++) Aacc[mb][t] = (float4v){0.f, 0.f, 0.f, 0.f};
    }

    // stage(t2) -> buffer kbuf: 2 K-granules + 2 V-granules per wave (4 DMAs)
    auto STAGE = [&](int t2, int kbuf) {
        const int kb = kbuf * 4096;
        #pragma unroll
        for (int h = 0; h < 2; h++) {
            const int g = wave * 2 + h;
            gload_lds16(&Kp[(size_t)t2 * 4096 + g * 512 + lane * 8], &LDS[kb + g * 512]);
            gload_lds16(&Vp[(size_t)t2 * 4096 + g * 512 + lane * 8], &LDS[12288 + kb + g * 512]);
        }
    };

    STAGE(0, 0);
    STAGE(1, 1);

    int cur = 0, nx2 = 2;   // kt%3 and (kt+2)%3
    for (int kt = 0; kt < 32; kt++) {
        if (kt < 31) { asm volatile("s_waitcnt vmcnt(4)" ::: "memory"); }
        else         { asm volatile("s_waitcnt vmcnt(0)" ::: "memory"); }
        __builtin_amdgcn_sched_barrier(0);
        __builtin_amdgcn_s_barrier();          // stage(kt) resident; kt-1 reads done
        __builtin_amdgcn_sched_barrier(0);

        const short* KB = &LDS[cur * 4096];
        const short* VB = &LDS[12288 + cur * 4096];

        #pragma unroll
        for (int c2 = 0; c2 < 2; c2++) {
            union AE { unsigned u[4]; short8 s; };
            AE ae[2];
            #pragma unroll
            for (int tn2 = 0; tn2 < 2; tn2++) {
                const int row = (c2 * 2 + tn2) * 16 + l15;
                const short* rp = &KB[row * 64];
                short8 b0 = *(const short8*)&rp[(quad ^ r7) << 3];
                short8 b1 = *(const short8*)&rp[((4 + quad) ^ r7) << 3];
                #pragma unroll
                for (int nb = 0; nb < 2; nb++) {
                    float4v s = (float4v){0.f, 0.f, 0.f, 0.f};
                    s = __builtin_amdgcn_mfma_f32_16x16x32_bf16(b0, aq[nb][0], s, 0, 0, 0);
                    s = __builtin_amdgcn_mfma_f32_16x16x32_bf16(b1, aq[nb][1], s, 0, 0, 0);
                    ae[nb].u[tn2 * 2]     = pk2(EXP2F(s[0]), EXP2F(s[1]));
                    ae[nb].u[tn2 * 2 + 1] = pk2(EXP2F(s[2]), EXP2F(s[3]));
                }
            }
            __builtin_amdgcn_s_setprio(1);
            Lacc[0] = __builtin_amdgcn_mfma_f32_16x16x32_bf16(ae[0].s, onesf, Lacc[0], 0, 0, 0);
            Lacc[1] = __builtin_amdgcn_mfma_f32_16x16x32_bf16(ae[1].s, onesf, Lacc[1], 0, 0, 0);
            #pragma unroll
            for (int tn = 0; tn < 4; tn++) {
                const int d = tn * 16 + l15;
                short8 bv = *(const short8*)&VB[d * 64 + (((c2 * 4 + quad) ^ r7) << 3)];
                Aacc[0][tn] = __builtin_amdgcn_mfma_f32_16x16x32_bf16(ae[0].s, bv, Aacc[0][tn], 0, 0, 0);
                Aacc[1][tn] = __builtin_amdgcn_mfma_f32_16x16x32_bf16(ae[1].s, bv, Aacc[1][tn], 0, 0, 0);
            }
            __builtin_amdgcn_s_setprio(0);
        }

        if (kt < 30) STAGE(kt + 2, nx2);       // overwrite buffer last read at kt-1
        cur = (cur == 2) ? 0 : cur + 1;
        nx2 = (nx2 == 2) ? 0 : nx2 + 1;
    }

    // epilogue: wave-local. Lacc[mb][r] (at l15==0) is already the FULL row sum.
    const int b = bh / HEADS, hh = bh - (bh / HEADS) * HEADS;
    #pragma unroll
    for (int mb = 0; mb < 2; mb++)
        #pragma unroll
        for (int r = 0; r < 4; r++) {
            float il = 1.f / __shfl(Lacc[mb][r], lane & 48, 64);
            int row = qt * 128 + wq + mb * 16 + quad * 4 + r;
            int tok = b * SEQ + row;
            #pragma unroll
            for (int tn = 0; tn < 4; tn++) {
                int d = tn * 16 + l15;
                float vs = Vsum[bh * 64 + d];
                float val = (vs + Aacc[mb][tn][r] * il) * (1.f / 2049.f);
                Ow[(size_t)tok * 768 + hh * 64 + d] = f2b(val);
            }
        }
}

extern "C" void kernel_launch(void* const* d_in, const int* in_sizes, int n_in,
                              void* d_out, int out_size, void* d_ws, size_t ws_size,
                              hipStream_t stream) {
    const float* x      = (const float*)d_in[0];
    const float* w_qkv  = (const float*)d_in[1];
    const float* w_proj = (const float*)d_in[2];
    const float* b_proj = (const float*)d_in[3];
    float* out = (float*)d_out;

    char* ws = (char*)d_ws;
    size_t off = 0;
    auto alloc = [&](size_t bytes) {
        void* p = ws + off;
        off += (bytes + 255) & ~(size_t)255;
        return p;
    };
    short* x_bf  = (short*)alloc((size_t)TOK * DIM * 2);
    short* wq_bf = (short*)alloc((size_t)3 * DIM * DIM * 2);
    short* wp_bf = (short*)alloc((size_t)DIM * DIM * 2);
    short* Qw    = (short*)alloc((size_t)BHN * SEQ * 64 * 2);
    short* Kw    = (short*)alloc((size_t)BHN * SEQ * 64 * 2);
    short* Vw    = (short*)alloc((size_t)BHN * SEQ * 64 * 2);
    short* Ow    = (short*)alloc((size_t)TOK * DIM * 2);
    float* Vsum  = (float*)alloc((size_t)BHN * 64 * 4);

    int nx4 = TOK * DIM / 4, nq4 = 3 * DIM * DIM / 4, np4 = DIM * DIM / 4;
    int tot4 = nx4 + nq4 + np4;
    cast_all<<<tot4 / 256, 256, 0, stream>>>(x, w_qkv, w_proj, x_bf, wq_bf, wp_bf, Vsum, nx4, nq4);

    gemm_qkv<<<1152, 256, 0, stream>>>(x_bf, wq_bf, Qw, Kw, Vw, Vsum);

    attn_kernel<<<BHN * 16, 256, 0, stream>>>(Qw, Kw, Vw, Vsum, Ow);

    gemm_proj<<<768, 256, 0, stream>>>(Ow, wp_bf, b_proj, out);
}

// Round 15
// 196.145 us; speedup vs baseline: 1.2302x; 1.0129x over previous
//
#include <hip/hip_runtime.h>
#include <hip/hip_bf16.h>

#define DIM 768
#define HEADS 12
#define HD 64
#define SEQ 2048
#define BATCH 4
#define BHN 48          // BATCH*HEADS
#define TOK 8192        // BATCH*SEQ

#if __has_builtin(__builtin_amdgcn_exp2f)
#define EXP2F __builtin_amdgcn_exp2f
#else
#define EXP2F exp2f
#endif
// exp(s*0.125) = 2^(s * 0.125 * log2(e)); folded into Q at the QKV epilogue.
#define EXP_C 0.1803368801111244f

using short8  = __attribute__((ext_vector_type(8))) short;
using short4v = __attribute__((ext_vector_type(4))) short;
using float4v = __attribute__((ext_vector_type(4))) float;

__device__ __forceinline__ short f2b(float f) {
    union { float f; unsigned u; } v; v.f = f;
    unsigned r = v.u + 0x7FFF + ((v.u >> 16) & 1);
    return (short)(r >> 16);
}
__device__ __forceinline__ float b2f(short s) {
    union { unsigned u; float f; } v;
    v.u = ((unsigned)(unsigned short)s) << 16;
    return v.f;
}
// pack two floats to bf16x2 in ONE instruction (v_cvt_pk_bf16_f32, RNE).
// Replaces the old 3-op add/add/perm sequence; RNE matches f2b's rounding.
__device__ __forceinline__ unsigned pk2(float a, float b) {
    unsigned r;
    asm("v_cvt_pk_bf16_f32 %0, %1, %2" : "=v"(r) : "v"(a), "v"(b));
    return r;
}

// async global->LDS copy, 16B per lane; LDS dest = uniform base + lane*16
typedef const __attribute__((address_space(1))) unsigned GU;
typedef __attribute__((address_space(3))) unsigned LU;
__device__ __forceinline__ void gload_lds16(const short* g, short* l) {
    __builtin_amdgcn_global_load_lds((GU*)g, (LU*)l, 16, 0, 0);
}

// ---------------- fp32 -> bf16 cast (+ Vsum zeroing), one launch ----------------
__global__ void cast_all(const float* __restrict__ x, const float* __restrict__ wq,
                         const float* __restrict__ wp,
                         short* __restrict__ xb, short* __restrict__ wqb,
                         short* __restrict__ wpb, float* __restrict__ Vsum,
                         int nx4, int nq4) {
    int i = blockIdx.x * 256 + threadIdx.x;
    if (i < BHN * 64) Vsum[i] = 0.f;
    const float* in; short* out; int j = i;
    if (i < nx4)            { in = x;  out = xb;  }
    else if (i < nx4 + nq4) { in = wq; out = wqb; j = i - nx4; }
    else                    { in = wp; out = wpb; j = i - nx4 - nq4; }
    float4 f = ((const float4*)in)[j];
    short4 o;
    o.x = f2b(f.x); o.y = f2b(f.y); o.z = f2b(f.z); o.w = f2b(f.w);
    ((short4*)out)[j] = o;
}

// ---------------- QKV GEMM, 128x128 tile, BK=32 ring-of-3 pipeline ----------------
// T3+T4: 3 LDS buffers (48 KB), ONE s_barrier per K-step, counted vmcnt(4)
// (next step's 4 staging DMAs stay in flight across the barrier), STAGE(t+2)
// issued at step end overwrites the buffer last read at t-1.
// Output layouts: attn's pre-swizzled LDS images + fused Vsum.
__global__ __launch_bounds__(256, 3)
void gemm_qkv(const short* __restrict__ A, const short* __restrict__ Bw,
              short* __restrict__ Qw, short* __restrict__ Kw, short* __restrict__ Vw,
              float* __restrict__ Vsum)
{
    __shared__ __align__(16) short As[3][128 * 32];   // 24 KB
    __shared__ __align__(16) short Bs[3][128 * 32];   // 24 KB -> 48 KB total

    const int tid  = threadIdx.x;
    const int lane = tid & 63;
    const int wave = tid >> 6;
    const int wm = (wave >> 1) * 64, wn = (wave & 1) * 64;
    const int l15 = lane & 15, quad = lane >> 4;

    const int gid = blockIdx.x;
    const int w   = gid >> 3;
    const int ybl = (gid & 7) * 8 + (w & 7);   // 0..63 token block
    const int xbl = w >> 3;                    // 0..17 col block

    const bool vpart = (xbl >= 12);
    const short* rowsP = vpart ? (Bw + 1536 * 768) : A;   // Wv rows | x tokens
    const short* colsP = vpart ? A : Bw;                  // x tokens | W rows
    const int m0 = vpart ? (xbl - 12) * 128 : ybl * 128;
    const int n0 = vpart ? ybl * 128 : xbl * 128;
    const int K = DIM;

    float4v acc[4][4];
    #pragma unroll
    for (int i = 0; i < 4; i++)
        #pragma unroll
        for (int j = 0; j < 4; j++)
            acc[i][j] = (float4v){0.f, 0.f, 0.f, 0.f};

    const int G0 = wave * 128 + lane;
    const int G1 = G0 + 64;
    const int rA0 = G0 >> 2, cA0 = (G0 & 3) * 8;
    const int rA1 = G1 >> 2, cA1 = (G1 & 3) * 8;
    const int ldsoff = wave * 1024;

    // stage K-step t (32 cols) into ring buffer buf: 4 DMAs per wave
    auto STAGE = [&](int t, int buf) {
        const int kc = t * 32;
        gload_lds16(&rowsP[(size_t)(m0 + rA0) * K + kc + cA0], &As[buf][ldsoff]);
        gload_lds16(&rowsP[(size_t)(m0 + rA1) * K + kc + cA1], &As[buf][ldsoff + 512]);
        gload_lds16(&colsP[(size_t)(n0 + rA0) * K + kc + cA0], &Bs[buf][ldsoff]);
        gload_lds16(&colsP[(size_t)(n0 + rA1) * K + kc + cA1], &Bs[buf][ldsoff + 512]);
    };

    STAGE(0, 0);
    STAGE(1, 1);

    int cur = 0, nx2 = 2;
    for (int t = 0; t < 24; t++) {
        if (t < 23) { asm volatile("s_waitcnt vmcnt(4)" ::: "memory"); }
        else        { asm volatile("s_waitcnt vmcnt(0)" ::: "memory"); }
        __builtin_amdgcn_sched_barrier(0);
        __builtin_amdgcn_s_barrier();          // stage(t) resident; t-1 reads done
        __builtin_amdgcn_sched_barrier(0);

        short8 af[4], bfr[4];
        #pragma unroll
        for (int tt = 0; tt < 4; tt++) {
            af[tt]  = *(const short8*)&As[cur][(wm + tt * 16 + l15) * 32 + quad * 8];
            bfr[tt] = *(const short8*)&Bs[cur][(wn + tt * 16 + l15) * 32 + quad * 8];
        }
        #pragma unroll
        for (int tm = 0; tm < 4; tm++)
            #pragma unroll
            for (int tn = 0; tn < 4; tn++)
                acc[tm][tn] = __builtin_amdgcn_mfma_f32_16x16x32_bf16(af[tm], bfr[tn], acc[tm][tn], 0, 0, 0);

        if (t < 22) STAGE(t + 2, nx2);         // overwrite buffer last read at t-1
        cur = (cur == 2) ? 0 : cur + 1;
        nx2 = (nx2 == 2) ? 0 : nx2 + 1;
    }

    #pragma unroll
    for (int tm = 0; tm < 4; tm++)
        #pragma unroll
        for (int tn = 0; tn < 4; tn++)
            #pragma unroll
            for (int r = 0; r < 4; r++) {
                int row = m0 + wm + tm * 16 + quad * 4 + r;
                int col = n0 + wn + tn * 16 + l15;
                float v = acc[tm][tn][r];
                if (vpart) {
                    int hh = row >> 6, d = row & 63;
                    int b = col >> 11, n = col & 2047;
                    int bh = b * HEADS + hh;
                    int t2 = n >> 6, c2h = (n >> 5) & 1, wk = n & 31;
                    int slot = ((wk & 15) >> 2) * 8 + ((wk & 16) >> 2) + (wk & 3);
                    int g2 = c2h * 4 + (slot >> 3);
                    int gp2 = g2 ^ (d & 7);
                    Vw[(size_t)bh * (SEQ * 64) + t2 * 4096 + d * 64 + gp2 * 8 + (slot & 7)] = f2b(v);
                } else {
                    int hh = (col & 767) >> 6, d = col & 63;
                    int b = row >> 11, n = row & 2047;
                    int bh = b * HEADS + hh;
                    size_t idx = (size_t)bh * (SEQ * 64) + (size_t)n * 64
                               + (((d >> 3) ^ (n & 7)) << 3) + (d & 7);
                    if (col < 768) Qw[idx] = f2b(v * EXP_C);
                    else           Kw[idx] = f2b(v);
                }
            }

    // fused vsum: partial column sums over this block's 64 tokens (per wave-half)
    if (vpart) {
        const int bb = n0 >> 11;   // batch of this block's tokens
        #pragma unroll
        for (int tm = 0; tm < 4; tm++)
            #pragma unroll
            for (int r = 0; r < 4; r++) {
                float s4 = (acc[tm][0][r] + acc[tm][1][r]) + (acc[tm][2][r] + acc[tm][3][r]);
                #pragma unroll
                for (int m = 1; m < 16; m <<= 1) s4 += __shfl_xor(s4, m, 64);
                if (l15 == 0) {
                    int row = m0 + wm + tm * 16 + quad * 4 + r;
                    int hh = row >> 6, d = row & 63;
                    atomicAdd(&Vsum[(bb * HEADS + hh) * 64 + d], s4);
                }
            }
    }
}

// ---------------- proj GEMM, 128x64 tile, BK=32 ring-of-3 pipeline ----------------
__global__ __launch_bounds__(256, 4)
void gemm_proj(const short* __restrict__ A, const short* __restrict__ Bw,
               const float* __restrict__ bias, float* __restrict__ Out)
{
    __shared__ __align__(16) short As[3][128 * 32];   // 24 KB
    __shared__ __align__(16) short Bs[3][64 * 32];    // 12 KB -> 36 KB total

    const int tid  = threadIdx.x;
    const int lane = tid & 63;
    const int wave = tid >> 6;
    const int wm = (wave >> 1) * 64, wn = (wave & 1) * 32;
    const int l15 = lane & 15, quad = lane >> 4;

    const int gid = blockIdx.x;             // 0..767
    const int w   = gid >> 3;               // 0..95
    const int ybl = (gid & 7) * 8 + (w & 7);   // 0..63 token block
    const int xbl = w >> 3;                    // 0..11 col block
    const int m0 = ybl * 128, n0 = xbl * 64;
    const int K = DIM;

    float4v acc[4][2];
    #pragma unroll
    for (int i = 0; i < 4; i++)
        #pragma unroll
        for (int j = 0; j < 2; j++)
            acc[i][j] = (float4v){0.f, 0.f, 0.f, 0.f};

    const int GA0 = wave * 128 + lane, GA1 = GA0 + 64;
    const int rA0 = GA0 >> 2, cA0 = (GA0 & 3) * 8;
    const int rA1 = GA1 >> 2, cA1 = (GA1 & 3) * 8;
    const int GB0 = wave * 64 + lane;
    const int rB0 = GB0 >> 2, cB0 = (GB0 & 3) * 8;
    const int ldsoffA = wave * 1024, ldsoffB = wave * 512;

    // stage K-step t into ring buffer buf: 3 DMAs per wave (2 A + 1 B)
    auto STAGE = [&](int t, int buf) {
        const int kc = t * 32;
        gload_lds16(&A [(size_t)(m0 + rA0) * K + kc + cA0], &As[buf][ldsoffA]);
        gload_lds16(&A [(size_t)(m0 + rA1) * K + kc + cA1], &As[buf][ldsoffA + 512]);
        gload_lds16(&Bw[(size_t)(n0 + rB0) * K + kc + cB0], &Bs[buf][ldsoffB]);
    };

    STAGE(0, 0);
    STAGE(1, 1);

    int cur = 0, nx2 = 2;
    for (int t = 0; t < 24; t++) {
        if (t < 23) { asm volatile("s_waitcnt vmcnt(3)" ::: "memory"); }
        else        { asm volatile("s_waitcnt vmcnt(0)" ::: "memory"); }
        __builtin_amdgcn_sched_barrier(0);
        __builtin_amdgcn_s_barrier();
        __builtin_amdgcn_sched_barrier(0);

        short8 af[4], bfr[2];
        #pragma unroll
        for (int tt = 0; tt < 4; tt++)
            af[tt] = *(const short8*)&As[cur][(wm + tt * 16 + l15) * 32 + quad * 8];
        #pragma unroll
        for (int tt = 0; tt < 2; tt++)
            bfr[tt] = *(const short8*)&Bs[cur][(wn + tt * 16 + l15) * 32 + quad * 8];
        #pragma unroll
        for (int tm = 0; tm < 4; tm++)
            #pragma unroll
            for (int tn = 0; tn < 2; tn++)
                acc[tm][tn] = __builtin_amdgcn_mfma_f32_16x16x32_bf16(af[tm], bfr[tn], acc[tm][tn], 0, 0, 0);

        if (t < 22) STAGE(t + 2, nx2);
        cur = (cur == 2) ? 0 : cur + 1;
        nx2 = (nx2 == 2) ? 0 : nx2 + 1;
    }

    #pragma unroll
    for (int tm = 0; tm < 4; tm++)
        #pragma unroll
        for (int tn = 0; tn < 2; tn++)
            #pragma unroll
            for (int r = 0; r < 4; r++) {
                int row = m0 + wm + tm * 16 + quad * 4 + r;
                int col = n0 + wn + tn * 16 + l15;
                Out[(size_t)row * 768 + col] = acc[tm][tn][r] + bias[col];
            }
}

// ---------------- fused double-softmax attention ----------------
// Round-25 = round-9 structure (best measured) + v_cvt_pk_bf16_f32 pack:
// pk2 drops from 3 VALU ops to 1 (16 calls/kt/wave -> saves 32 ops/kt/wave
// on the exp->pack critical chain). RNE rounding, consistent with f2b.
__global__ __launch_bounds__(256, 3)
void attn_kernel(const short* __restrict__ Qw, const short* __restrict__ Kw,
                 const short* __restrict__ Vw, const float* __restrict__ Vsum,
                 short* __restrict__ Ow)
{
    __shared__ __align__(16) short LDS[24576];  // 48 KB: K[3][4096] | V[3][4096]

    const int tid  = threadIdx.x;
    const int lane = tid & 63, wave = tid >> 6;
    const int l15 = lane & 15, quad = lane >> 4;
    const int r7  = l15 & 7;
    // XCD-locality: 6 heads per XCD; the 16 q-blocks of a head share its K/V in L2.
    const int bid = blockIdx.x;
    const int ii  = bid >> 3;                  // 0..95
    const int bh  = (bid & 7) * 6 + (ii >> 4); // head
    const int qt  = ii & 15;                   // q-tile index
    const int wq  = wave * 32;                 // wave's q-row base within block

    const short* Qp = Qw + (size_t)bh * (SEQ * 64) + qt * 8192;
    const short* Kp = Kw + (size_t)bh * (SEQ * 64);
    const short* Vp = Vw + (size_t)bh * (SEQ * 64);

    // ones B-fragment for 16x16x32: col 0 only (l15==0), all 8 k-slots = 1.0
    short8 onesf;
    #pragma unroll
    for (int j = 0; j < 8; j++) onesf[j] = (l15 == 0) ? (short)0x3F80 : (short)0;

    // ---- stage Q tile image (16 granules), read fragments, then free the LDS ----
    #pragma unroll
    for (int h = 0; h < 4; h++) {
        const int g = wave * 4 + h;
        gload_lds16(&Qp[g * 512 + lane * 8], &LDS[g * 512]);
    }
    __syncthreads();   // full drain ok here (prologue only)
    short8 aq[2][2];
    #pragma unroll
    for (int nb = 0; nb < 2; nb++)
        #pragma unroll
        for (int kk = 0; kk < 2; kk++) {
            int r = wq + nb * 16 + l15;
            aq[nb][kk] = *(const short8*)&LDS[r * 64 + (((kk * 4 + quad) ^ r7) << 3)];
        }
    __syncthreads();   // all waves done reading Q before K/V staging overwrites

    float4v Aacc[2][4], Lacc[2];
    #pragma unroll
    for (int mb = 0; mb < 2; mb++) {
        Lacc[mb] = (float4v){0.f, 0.f, 0.f, 0.f};
        #pragma unroll
        for (int t = 0; t < 4; t++) Aacc[mb][t] = (float4v){0.f, 0.f, 0.f, 0.f};
    }

    // stage(t2) -> buffer kbuf: 2 K-granules + 2 V-granules per wave (4 DMAs)
    auto STAGE = [&](int t2, int kbuf) {
        const int kb = kbuf * 4096;
        #pragma unroll
        for (int h = 0; h < 2; h++) {
            const int g = wave * 2 + h;
            gload_lds16(&Kp[(size_t)t2 * 4096 + g * 512 + lane * 8], &LDS[kb + g * 512]);
            gload_lds16(&Vp[(size_t)t2 * 4096 + g * 512 + lane * 8], &LDS[12288 + kb + g * 512]);
        }
    };

    STAGE(0, 0);
    STAGE(1, 1);

    int cur = 0, nx2 = 2;   // kt%3 and (kt+2)%3
    for (int kt = 0; kt < 32; kt++) {
        if (kt < 31) { asm volatile("s_waitcnt vmcnt(4)" ::: "memory"); }
        else         { asm volatile("s_waitcnt vmcnt(0)" ::: "memory"); }
        __builtin_amdgcn_sched_barrier(0);
        __builtin_amdgcn_s_barrier();          // stage(kt) resident; kt-1 reads done
        __builtin_amdgcn_sched_barrier(0);

        const short* KB = &LDS[cur * 4096];
        const short* VB = &LDS[12288 + cur * 4096];

        #pragma unroll
        for (int c2 = 0; c2 < 2; c2++) {
            union AE { unsigned u[4]; short8 s; };
            AE ae[2];
            #pragma unroll
            for (int tn2 = 0; tn2 < 2; tn2++) {
                const int row = (c2 * 2 + tn2) * 16 + l15;
                const short* rp = &KB[row * 64];
                short8 b0 = *(const short8*)&rp[(quad ^ r7) << 3];
                short8 b1 = *(const short8*)&rp[((4 + quad) ^ r7) << 3];
                #pragma unroll
                for (int nb = 0; nb < 2; nb++) {
                    float4v s = (float4v){0.f, 0.f, 0.f, 0.f};
                    s = __builtin_amdgcn_mfma_f32_16x16x32_bf16(b0, aq[nb][0], s, 0, 0, 0);
                    s = __builtin_amdgcn_mfma_f32_16x16x32_bf16(b1, aq[nb][1], s, 0, 0, 0);
                    ae[nb].u[tn2 * 2]     = pk2(EXP2F(s[0]), EXP2F(s[1]));
                    ae[nb].u[tn2 * 2 + 1] = pk2(EXP2F(s[2]), EXP2F(s[3]));
                }
            }
            __builtin_amdgcn_s_setprio(1);
            Lacc[0] = __builtin_amdgcn_mfma_f32_16x16x32_bf16(ae[0].s, onesf, Lacc[0], 0, 0, 0);
            Lacc[1] = __builtin_amdgcn_mfma_f32_16x16x32_bf16(ae[1].s, onesf, Lacc[1], 0, 0, 0);
            #pragma unroll
            for (int tn = 0; tn < 4; tn++) {
                const int d = tn * 16 + l15;
                short8 bv = *(const short8*)&VB[d * 64 + (((c2 * 4 + quad) ^ r7) << 3)];
                Aacc[0][tn] = __builtin_amdgcn_mfma_f32_16x16x32_bf16(ae[0].s, bv, Aacc[0][tn], 0, 0, 0);
                Aacc[1][tn] = __builtin_amdgcn_mfma_f32_16x16x32_bf16(ae[1].s, bv, Aacc[1][tn], 0, 0, 0);
            }
            __builtin_amdgcn_s_setprio(0);
        }

        if (kt < 30) STAGE(kt + 2, nx2);       // overwrite buffer last read at kt-1
        cur = (cur == 2) ? 0 : cur + 1;
        nx2 = (nx2 == 2) ? 0 : nx2 + 1;
    }

    // epilogue: wave-local. Lacc[mb][r] (at l15==0) is already the FULL row sum.
    const int b = bh / HEADS, hh = bh - (bh / HEADS) * HEADS;
    #pragma unroll
    for (int mb = 0; mb < 2; mb++)
        #pragma unroll
        for (int r = 0; r < 4; r++) {
            float il = 1.f / __shfl(Lacc[mb][r], lane & 48, 64);
            int row = qt * 128 + wq + mb * 16 + quad * 4 + r;
            int tok = b * SEQ + row;
            #pragma unroll
            for (int tn = 0; tn < 4; tn++) {
                int d = tn * 16 + l15;
                float vs = Vsum[bh * 64 + d];
                float val = (vs + Aacc[mb][tn][r] * il) * (1.f / 2049.f);
                Ow[(size_t)tok * 768 + hh * 64 + d] = f2b(val);
            }
        }
}

extern "C" void kernel_launch(void* const* d_in, const int* in_sizes, int n_in,
                              void* d_out, int out_size, void* d_ws, size_t ws_size,
                              hipStream_t stream) {
    const float* x      = (const float*)d_in[0];
    const float* w_qkv  = (const float*)d_in[1];
    const float* w_proj = (const float*)d_in[2];
    const float* b_proj = (const float*)d_in[3];
    float* out = (float*)d_out;

    char* ws = (char*)d_ws;
    size_t off = 0;
    auto alloc = [&](size_t bytes) {
        void* p = ws + off;
        off += (bytes + 255) & ~(size_t)255;
        return p;
    };
    short* x_bf  = (short*)alloc((size_t)TOK * DIM * 2);
    short* wq_bf = (short*)alloc((size_t)3 * DIM * DIM * 2);
    short* wp_bf = (short*)alloc((size_t)DIM * DIM * 2);
    short* Qw    = (short*)alloc((size_t)BHN * SEQ * 64 * 2);
    short* Kw    = (short*)alloc((size_t)BHN * SEQ * 64 * 2);
    short* Vw    = (short*)alloc((size_t)BHN * SEQ * 64 * 2);
    short* Ow    = (short*)alloc((size_t)TOK * DIM * 2);
    float* Vsum  = (float*)alloc((size_t)BHN * 64 * 4);

    int nx4 = TOK * DIM / 4, nq4 = 3 * DIM * DIM / 4, np4 = DIM * DIM / 4;
    int tot4 = nx4 + nq4 + np4;
    cast_all<<<tot4 / 256, 256, 0, stream>>>(x, w_qkv, w_proj, x_bf, wq_bf, wp_bf, Vsum, nx4, nq4);

    gemm_qkv<<<1152, 256, 0, stream>>>(x_bf, wq_bf, Qw, Kw, Vw, Vsum);

    attn_kernel<<<BHN * 16, 256, 0, stream>>>(Qw, Kw, Vw, Vsum, Ow);

    gemm_proj<<<768, 256, 0, stream>>>(Ow, wp_bf, b_proj, out);
}